// Round 3
// baseline (1382.119 us; speedup 1.0000x reference)
//
#include <hip/hip_runtime.h>

#define IN_F 4096
#define OUT_F 4096
#define RANK 64
#define M_TOT 8192

// f16 round-trip: the value of (float16)v as f32. Matches numpy astype(f16) RNE.
__device__ __forceinline__ float f16r(float v) { return (float)(_Float16)v; }

// 2:4 soft-threshold one aligned group of 4, scale, f16-round. Outputs are the
// exact f32 values of the f16-cast sparse weights.
__device__ __forceinline__ void thresh4(const float* __restrict__ p, float scale,
                                        float* __restrict__ o) {
    const float v0 = p[0], v1 = p[1], v2 = p[2], v3 = p[3];
    const float m0 = fabsf(v0), m1 = fabsf(v1), m2 = fabsf(v2), m3 = fabsf(v3);
    const float lo1 = fminf(m0, m1), hi1 = fmaxf(m0, m1);
    const float lo2 = fminf(m2, m3), hi2 = fmaxf(m2, m3);
    const float t = fminf(fmaxf(lo1, lo2), fminf(hi1, hi2)); // 2nd-smallest magnitude
    o[0] = f16r(copysignf(fmaxf(m0 - t, 0.0f), v0) * scale);
    o[1] = f16r(copysignf(fmaxf(m1 - t, 0.0f), v1) * scale);
    o[2] = f16r(copysignf(fmaxf(m2 - t, 0.0f), v2) * scale);
    o[3] = f16r(copysignf(fmaxf(m3 - t, 0.0f), v3) * scale);
}

// ---------------------------------------------------------------------------
// Pure-scalar bisection probe. No MFMA, no d_ws, no vector-pointer casts.
// Block = 256 threads owns 16 M-rows; grid = 512.
// Phase 1: xp[16][64] (f16-rounded, held as f32) in LDS.
//   thread t -> column n = t&63, rows mb..mb+3 where mb = (t>>6)*4.
// Phase 2: out[16][4096], 256 cells per thread, 64-length dots.
// All products are f32 multiplies of f16-rounded values == exact f16*f16 -> f32.
// ---------------------------------------------------------------------------
__global__ __launch_bounds__(256) void probe_kernel(
    const float* __restrict__ x, const float* __restrict__ w_in,
    const float* __restrict__ w_out, const float* __restrict__ bias,
    const float* __restrict__ s_in_p, const float* __restrict__ s_out_p,
    float* __restrict__ out)
{
    __shared__ float xpl[16][RANK];
    const int t = threadIdx.x;
    const int m0 = blockIdx.x * 16;
    const float s_in = *s_in_p;
    const float s_out = *s_out_p;

    // ---------------- phase 1: xp = f16(x) @ f16(st24(w_in)*s_in)^T ---------
    {
        const int n = t & 63;
        const int mb = (t >> 6) * 4;
        const float* wr = w_in + (size_t)n * IN_F;
        const float* x0 = x + (size_t)(m0 + mb) * IN_F;
        float acc0 = 0.f, acc1 = 0.f, acc2 = 0.f, acc3 = 0.f;
        for (int k = 0; k < IN_F; k += 4) {
            float w16[4];
            thresh4(wr + k, s_in, w16);
            #pragma unroll
            for (int j = 0; j < 4; ++j) {
                const float wv = w16[j];
                acc0 = fmaf(f16r(x0[k + j]),             wv, acc0);
                acc1 = fmaf(f16r(x0[IN_F + k + j]),      wv, acc1);
                acc2 = fmaf(f16r(x0[2 * IN_F + k + j]),  wv, acc2);
                acc3 = fmaf(f16r(x0[3 * IN_F + k + j]),  wv, acc3);
            }
        }
        xpl[mb + 0][n] = f16r(acc0);   // reference casts xp to f16 before GEMM2
        xpl[mb + 1][n] = f16r(acc1);
        xpl[mb + 2][n] = f16r(acc2);
        xpl[mb + 3][n] = f16r(acc3);
    }
    __syncthreads();

    // ---------------- phase 2: out = (xp16 @ f16(st24(w_out)*s_out)^T)/64 ---
    for (int cell = t; cell < 16 * OUT_F; cell += 256) {
        const int m = cell >> 12;          // 0..15
        const int col = cell & (OUT_F - 1);
        const float* wo = w_out + (size_t)col * RANK;
        float acc = 0.f;
        for (int g = 0; g < RANK; g += 4) {
            float w16[4];
            thresh4(wo + g, s_out, w16);
            #pragma unroll
            for (int j = 0; j < 4; ++j)
                acc = fmaf(xpl[m][g + j], w16[j], acc);
        }
        out[(size_t)(m0 + m) * OUT_F + col] = (acc + bias[col]) * (1.0f / 64.0f);
    }
}

// ---------------------------------------------------------------------------
extern "C" void kernel_launch(void* const* d_in, const int* in_sizes, int n_in,
                              void* d_out, int out_size, void* d_ws, size_t ws_size,
                              hipStream_t stream) {
    (void)in_sizes; (void)n_in; (void)out_size; (void)d_ws; (void)ws_size;
    // Positional binding, exactly as documented (setup_inputs dict order).
    const float* x     = (const float*)d_in[0];
    const float* w_in  = (const float*)d_in[1];
    const float* w_out = (const float*)d_in[2];
    const float* bias  = (const float*)d_in[3];
    const float* s_in  = (const float*)d_in[4];
    const float* s_out = (const float*)d_in[5];

    probe_kernel<<<M_TOT / 16, 256, 0, stream>>>(
        x, w_in, w_out, bias, s_in, s_out, (float*)d_out);
}

// Round 5
// 154.777 us; speedup vs baseline: 8.9297x; 8.9297x over previous
//
#include <hip/hip_runtime.h>

typedef _Float16 half8 __attribute__((ext_vector_type(8)));
typedef float f32x4 __attribute__((ext_vector_type(4)));

#define IN_F 4096
#define OUT_F 4096
#define RANK 64
#define M_TOT 8192
#define KCHUNK 1024

// 2 aligned groups of 4: 2:4 soft-threshold, scale, cast f16 (MFMA B operand).
// VALIDATED: identical to round-4 phase D's B path (quiet 20x channel).
__device__ __forceinline__ half8 thresh8(const float* __restrict__ p, float scale) {
    half8 h;
    #pragma unroll
    for (int g = 0; g < 2; ++g) {
        f32x4 v = *(const f32x4*)(p + 4 * g);
        float m0 = fabsf(v[0]), m1 = fabsf(v[1]), m2 = fabsf(v[2]), m3 = fabsf(v[3]);
        float lo1 = fminf(m0, m1), hi1 = fmaxf(m0, m1);
        float lo2 = fminf(m2, m3), hi2 = fmaxf(m2, m3);
        float t = fminf(fmaxf(lo1, lo2), fminf(hi1, hi2)); // 2nd-smallest magnitude
        h[4 * g + 0] = (_Float16)(copysignf(fmaxf(m0 - t, 0.0f), v[0]) * scale);
        h[4 * g + 1] = (_Float16)(copysignf(fmaxf(m1 - t, 0.0f), v[1]) * scale);
        h[4 * g + 2] = (_Float16)(copysignf(fmaxf(m2 - t, 0.0f), v[2]) * scale);
        h[4 * g + 3] = (_Float16)(copysignf(fmaxf(m3 - t, 0.0f), v[3]) * scale);
    }
    return h;
}

// ---------------------------------------------------------------------------
// Fused kernel, validated-structure-only build.
// Block = 256 thr (4 waves) owns 16 M-rows; grid = 512.
// Phase 1: stage f16(x) K-chunk into LDS (scalar casts+stores = validated
//          phase-A op), then per-wave MFMA over its OWN 16 xp-columns
//          (N-split across waves; full K per wave; no cross-wave reduce).
//          A from LDS half8 load (validated phase-D op), B = thresh8 global.
// Phase 2: round-4 phase D verbatim (validated), minus the compare.
// MFMA 16x16x32_f16: A/B lane l elem j -> (free = l&15, k = (l>>4)*8 + j);
// D lane l reg r -> (Afree = (l>>4)*4 + r, Bfree = l&15).
// ---------------------------------------------------------------------------
__global__ __launch_bounds__(256) void loro_kernel(
    const float* __restrict__ x, const float* __restrict__ w_in,
    const float* __restrict__ w_out, const float* __restrict__ bias,
    const float* __restrict__ s_in_p, const float* __restrict__ s_out_p,
    float* __restrict__ out)
{
    __shared__ _Float16 xh[16][KCHUNK];   // 32 KiB: f16(x) K-chunk
    __shared__ _Float16 xpl[16][RANK];    // 2 KiB : f16 xp tile

    const int t    = threadIdx.x;
    const int wave = t >> 6;
    const int lane = t & 63;
    const int row  = lane & 15;
    const int kg   = lane >> 4;
    const int m0   = blockIdx.x * 16;
    const float s_in  = *s_in_p;
    const float s_out = *s_out_p;

    // ---------------- phase 1 ----------------
    // wave w owns xp columns n = w*16 + row (B free index = lane&15 = row).
    f32x4 acc1 = {0.f, 0.f, 0.f, 0.f};
    const float* wr = w_in + (size_t)(wave * 16 + row) * IN_F + kg * 8;

    for (int kc = 0; kc < IN_F; kc += KCHUNK) {
        __syncthreads();   // xh safe to overwrite (prev chunk's readers done)

        // cooperative stage: x[16][kc..kc+1023] -> f16 LDS.
        // thread t, iter i handles flat f = i*2048 + t*8 (8 consecutive).
        #pragma unroll
        for (int i = 0; i < 8; ++i) {
            const int f  = i * 2048 + t * 8;
            const int r  = f >> 10;
            const int cl = f & (KCHUNK - 1);
            const float* src = x + (size_t)(m0 + r) * IN_F + kc + cl;
            f32x4 a = *(const f32x4*)src;
            f32x4 b = *(const f32x4*)(src + 4);
            #pragma unroll
            for (int j = 0; j < 4; ++j) {
                xh[r][cl + j]     = (_Float16)a[j];   // scalar cast+store
                xh[r][cl + 4 + j] = (_Float16)b[j];   // (validated phase-A op)
            }
        }
        __syncthreads();

        #pragma unroll 4
        for (int k0 = 0; k0 < KCHUNK; k0 += 64) {
            half8 alo = *(const half8*)&xh[row][k0 + kg * 8];        // validated
            half8 ahi = *(const half8*)&xh[row][k0 + kg * 8 + 32];   // LDS A-load
            half8 blo = thresh8(wr + kc + k0,      s_in);
            half8 bhi = thresh8(wr + kc + k0 + 32, s_in);
            acc1 = __builtin_amdgcn_mfma_f32_16x16x32_f16(alo, blo, acc1, 0, 0, 0);
            acc1 = __builtin_amdgcn_mfma_f32_16x16x32_f16(ahi, bhi, acc1, 0, 0, 0);
        }
    }

    // D layout: Afree(m-local) = kg*4 + r, Bfree(n-local) = row.
    #pragma unroll
    for (int r = 0; r < 4; ++r)
        xpl[kg * 4 + r][wave * 16 + row] = (_Float16)acc1[r];
    __syncthreads();

    // ---------------- phase 2 (round-4 phase D verbatim) ----------------
    const half8 a_lo = *(const half8*)&xpl[row][kg * 8];
    const half8 a_hi = *(const half8*)&xpl[row][kg * 8 + 32];
    const float scaling = 1.0f / 64.0f;

    for (int c = 0; c < 16; ++c) {
        f32x4 acc[4] = {{0.f,0.f,0.f,0.f},{0.f,0.f,0.f,0.f},
                        {0.f,0.f,0.f,0.f},{0.f,0.f,0.f,0.f}};
        #pragma unroll
        for (int nt = 0; nt < 4; ++nt) {
            const float* wp = w_out
                + (size_t)(c * 256 + wave * 64 + nt * 16 + row) * RANK + kg * 8;
            half8 blo = thresh8(wp,      s_out);
            half8 bhi = thresh8(wp + 32, s_out);
            acc[nt] = __builtin_amdgcn_mfma_f32_16x16x32_f16(a_lo, blo, acc[nt], 0, 0, 0);
            acc[nt] = __builtin_amdgcn_mfma_f32_16x16x32_f16(a_hi, bhi, acc[nt], 0, 0, 0);
        }
        #pragma unroll
        for (int nt = 0; nt < 4; ++nt) {
            const int col = c * 256 + wave * 64 + nt * 16 + row;
            const float b = bias[col];
            #pragma unroll
            for (int r = 0; r < 4; ++r)
                out[(size_t)(m0 + kg * 4 + r) * OUT_F + col] = (acc[nt][r] + b) * scaling;
        }
    }
}

// ---------------------------------------------------------------------------
extern "C" void kernel_launch(void* const* d_in, const int* in_sizes, int n_in,
                              void* d_out, int out_size, void* d_ws, size_t ws_size,
                              hipStream_t stream) {
    (void)in_sizes; (void)n_in; (void)out_size; (void)d_ws; (void)ws_size;
    // Positional binding (validated by round-3 probe PASS).
    const float* x     = (const float*)d_in[0];
    const float* w_in  = (const float*)d_in[1];
    const float* w_out = (const float*)d_in[2];
    const float* bias  = (const float*)d_in[3];
    const float* s_in  = (const float*)d_in[4];
    const float* s_out = (const float*)d_in[5];

    loro_kernel<<<M_TOT / 16, 256, 0, stream>>>(
        x, w_in, w_out, bias, s_in, s_out, (float*)d_out);
}

// Round 6
// 92.012 us; speedup vs baseline: 15.0210x; 1.6821x over previous
//
#include <hip/hip_runtime.h>

typedef _Float16 half8 __attribute__((ext_vector_type(8)));
typedef float f32x4 __attribute__((ext_vector_type(4)));

#define IN_F 4096
#define OUT_F 4096
#define RANK 64
#define M_TOT 8192
#define KCHUNK 1024
#define NKC (IN_F / KCHUNK)

// 2 aligned groups of 4: 2:4 soft-threshold, scale, cast f16. VALIDATED (r4/r5).
__device__ __forceinline__ half8 thresh8(const float* __restrict__ p, float scale) {
    half8 h;
    #pragma unroll
    for (int g = 0; g < 2; ++g) {
        f32x4 v = *(const f32x4*)(p + 4 * g);
        float m0 = fabsf(v[0]), m1 = fabsf(v[1]), m2 = fabsf(v[2]), m3 = fabsf(v[3]);
        float lo1 = fminf(m0, m1), hi1 = fmaxf(m0, m1);
        float lo2 = fminf(m2, m3), hi2 = fmaxf(m2, m3);
        float t = fminf(fmaxf(lo1, lo2), fminf(hi1, hi2)); // 2nd-smallest magnitude
        h[4 * g + 0] = (_Float16)(copysignf(fmaxf(m0 - t, 0.0f), v[0]) * scale);
        h[4 * g + 1] = (_Float16)(copysignf(fmaxf(m1 - t, 0.0f), v[1]) * scale);
        h[4 * g + 2] = (_Float16)(copysignf(fmaxf(m2 - t, 0.0f), v[2]) * scale);
        h[4 * g + 3] = (_Float16)(copysignf(fmaxf(m3 - t, 0.0f), v[3]) * scale);
    }
    return h;
}

// ---------------------------------------------------------------------------
// prep: f16 sparse weights into d_ws. 65536 threads, each 2 groups of 4.
// tid < 32768 -> sw_in (64x4096), else sw_out (4096x64). Wave-uniform branch.
// ---------------------------------------------------------------------------
__global__ __launch_bounds__(256) void prep_kernel(
    const float* __restrict__ w_in, const float* __restrict__ w_out,
    const float* __restrict__ s_in_p, const float* __restrict__ s_out_p,
    _Float16* __restrict__ sw_in, _Float16* __restrict__ sw_out)
{
    const int tid = blockIdx.x * 256 + threadIdx.x;
    const int HALF = RANK * IN_F / 8;     // 32768
    const float* src; _Float16* dst; float sc; int g;
    if (tid < HALF) { src = w_in;  dst = sw_in;  sc = *s_in_p;  g = tid; }
    else            { src = w_out; dst = sw_out; sc = *s_out_p; g = tid - HALF; }
    half8 h = thresh8(src + (size_t)g * 8, sc);
    *(half8*)(dst + (size_t)g * 8) = h;
}

// ---------------------------------------------------------------------------
// Main fused kernel (fast path; weights pre-thresholded in d_ws).
// Block = 16 M-rows, 4 waves, grid = 512.
// Phase 1: x staged f32->f16 into double-buffered, XOR-swizzled LDS
//          (16B-block index kb stored at kb ^ (row&7)); wave w owns xp
//          columns w*16..w*16+15, full K, chained f32x4 accumulator.
// Phase 2: round-5 phase 2 verbatim, B = plain half8 loads from sw_out.
// MFMA 16x16x32_f16: A/B lane l elem j -> (free = l&15, k = (l>>4)*8 + j);
// D lane l reg r -> (Afree = (l>>4)*4 + r, Bfree = l&15).
// ---------------------------------------------------------------------------
__global__ __launch_bounds__(256) void loro_main(
    const float* __restrict__ x, const _Float16* __restrict__ sw_in,
    const _Float16* __restrict__ sw_out, const float* __restrict__ bias,
    float* __restrict__ out)
{
    __shared__ _Float16 xh[2][16][KCHUNK];   // 64 KiB, swizzled 16B blocks
    __shared__ _Float16 xpl[16][RANK];       // 2 KiB

    const int t    = threadIdx.x;
    const int wave = t >> 6;
    const int lane = t & 63;
    const int row  = lane & 15;
    const int kg   = lane >> 4;
    const int m0   = blockIdx.x * 16;

    // staging map: thread t, iter i -> row r = i*2 + (t>>7), 16B-block skb = t&127
    const int sr  = t >> 7;
    const int skb = t & 127;

    f32x4 ra[8], rb[8];

    auto issue = [&](int kc) {                    // global loads only (no use)
        #pragma unroll
        for (int i = 0; i < 8; ++i) {
            const float* src = x + (size_t)(m0 + i * 2 + sr) * IN_F + kc + skb * 8;
            ra[i] = *(const f32x4*)src;
            rb[i] = *(const f32x4*)(src + 4);
        }
    };
    auto cstore = [&](int buf) {                  // convert + swizzled b128 store
        #pragma unroll
        for (int i = 0; i < 8; ++i) {
            const int r = i * 2 + sr;
            half8 h;
            #pragma unroll
            for (int j = 0; j < 4; ++j) {
                h[j]     = (_Float16)ra[i][j];
                h[j + 4] = (_Float16)rb[i][j];
            }
            *(half8*)&xh[buf][r][(skb ^ (r & 7)) << 3] = h;
        }
    };

    // ---------------- phase 1 ----------------
    const _Float16* wr = sw_in + (size_t)(wave * 16 + row) * IN_F + kg * 8;
    f32x4 acc1 = {0.f, 0.f, 0.f, 0.f};

    issue(0);
    cstore(0);
    __syncthreads();
    int cur = 0;
    for (int kci = 0; kci < NKC; ++kci) {
        if (kci + 1 < NKC) issue((kci + 1) * KCHUNK);   // overlap with consume
        const int kc = kci * KCHUNK;
        #pragma unroll 4
        for (int k0 = 0; k0 < KCHUNK; k0 += 64) {
            const int kb = (k0 >> 3) + kg;
            half8 alo = *(const half8*)&xh[cur][row][(kb       ^ (row & 7)) << 3];
            half8 ahi = *(const half8*)&xh[cur][row][((kb + 4) ^ (row & 7)) << 3];
            half8 blo = *(const half8*)(wr + kc + k0);
            half8 bhi = *(const half8*)(wr + kc + k0 + 32);
            acc1 = __builtin_amdgcn_mfma_f32_16x16x32_f16(alo, blo, acc1, 0, 0, 0);
            acc1 = __builtin_amdgcn_mfma_f32_16x16x32_f16(ahi, bhi, acc1, 0, 0, 0);
        }
        if (kci + 1 < NKC) cstore(cur ^ 1);
        __syncthreads();
        cur ^= 1;
    }

    #pragma unroll
    for (int r = 0; r < 4; ++r)
        xpl[kg * 4 + r][wave * 16 + row] = (_Float16)acc1[r];
    __syncthreads();

    // ---------------- phase 2 (validated structure) ----------------
    const half8 a_lo = *(const half8*)&xpl[row][kg * 8];
    const half8 a_hi = *(const half8*)&xpl[row][kg * 8 + 32];
    const float scaling = 1.0f / 64.0f;

    for (int c = 0; c < 16; ++c) {
        f32x4 acc[4] = {{0.f,0.f,0.f,0.f},{0.f,0.f,0.f,0.f},
                        {0.f,0.f,0.f,0.f},{0.f,0.f,0.f,0.f}};
        #pragma unroll
        for (int nt = 0; nt < 4; ++nt) {
            const _Float16* wp = sw_out
                + (size_t)(c * 256 + wave * 64 + nt * 16 + row) * RANK + kg * 8;
            half8 blo = *(const half8*)wp;
            half8 bhi = *(const half8*)(wp + 32);
            acc[nt] = __builtin_amdgcn_mfma_f32_16x16x32_f16(a_lo, blo, acc[nt], 0, 0, 0);
            acc[nt] = __builtin_amdgcn_mfma_f32_16x16x32_f16(a_hi, bhi, acc[nt], 0, 0, 0);
        }
        #pragma unroll
        for (int nt = 0; nt < 4; ++nt) {
            const int col = c * 256 + wave * 64 + nt * 16 + row;
            const float b = bias[col];
            #pragma unroll
            for (int r = 0; r < 4; ++r)
                out[(size_t)(m0 + kg * 4 + r) * OUT_F + col] = (acc[nt][r] + b) * scaling;
        }
    }
}

// ---------------------------------------------------------------------------
// Fallback: round-5 kernel VERBATIM (passed at 155 us). Used if ws too small.
// ---------------------------------------------------------------------------
__global__ __launch_bounds__(256) void loro_fallback(
    const float* __restrict__ x, const float* __restrict__ w_in,
    const float* __restrict__ w_out, const float* __restrict__ bias,
    const float* __restrict__ s_in_p, const float* __restrict__ s_out_p,
    float* __restrict__ out)
{
    __shared__ _Float16 xh[16][KCHUNK];
    __shared__ _Float16 xpl[16][RANK];

    const int t    = threadIdx.x;
    const int wave = t >> 6;
    const int lane = t & 63;
    const int row  = lane & 15;
    const int kg   = lane >> 4;
    const int m0   = blockIdx.x * 16;
    const float s_in  = *s_in_p;
    const float s_out = *s_out_p;

    f32x4 acc1 = {0.f, 0.f, 0.f, 0.f};
    const float* wr = w_in + (size_t)(wave * 16 + row) * IN_F + kg * 8;

    for (int kc = 0; kc < IN_F; kc += KCHUNK) {
        __syncthreads();
        #pragma unroll
        for (int i = 0; i < 8; ++i) {
            const int f  = i * 2048 + t * 8;
            const int r  = f >> 10;
            const int cl = f & (KCHUNK - 1);
            const float* src = x + (size_t)(m0 + r) * IN_F + kc + cl;
            f32x4 a = *(const f32x4*)src;
            f32x4 b = *(const f32x4*)(src + 4);
            #pragma unroll
            for (int j = 0; j < 4; ++j) {
                xh[r][cl + j]     = (_Float16)a[j];
                xh[r][cl + 4 + j] = (_Float16)b[j];
            }
        }
        __syncthreads();

        #pragma unroll 4
        for (int k0 = 0; k0 < KCHUNK; k0 += 64) {
            half8 alo = *(const half8*)&xh[row][k0 + kg * 8];
            half8 ahi = *(const half8*)&xh[row][k0 + kg * 8 + 32];
            half8 blo = thresh8(wr + kc + k0,      s_in);
            half8 bhi = thresh8(wr + kc + k0 + 32, s_in);
            acc1 = __builtin_amdgcn_mfma_f32_16x16x32_f16(alo, blo, acc1, 0, 0, 0);
            acc1 = __builtin_amdgcn_mfma_f32_16x16x32_f16(ahi, bhi, acc1, 0, 0, 0);
        }
    }

    #pragma unroll
    for (int r = 0; r < 4; ++r)
        xpl[kg * 4 + r][wave * 16 + row] = (_Float16)acc1[r];
    __syncthreads();

    const half8 a_lo = *(const half8*)&xpl[row][kg * 8];
    const half8 a_hi = *(const half8*)&xpl[row][kg * 8 + 32];
    const float scaling = 1.0f / 64.0f;

    for (int c = 0; c < 16; ++c) {
        f32x4 acc[4] = {{0.f,0.f,0.f,0.f},{0.f,0.f,0.f,0.f},
                        {0.f,0.f,0.f,0.f},{0.f,0.f,0.f,0.f}};
        #pragma unroll
        for (int nt = 0; nt < 4; ++nt) {
            const float* wp = w_out
                + (size_t)(c * 256 + wave * 64 + nt * 16 + row) * RANK + kg * 8;
            half8 blo = thresh8(wp,      s_out);
            half8 bhi = thresh8(wp + 32, s_out);
            acc[nt] = __builtin_amdgcn_mfma_f32_16x16x32_f16(a_lo, blo, acc[nt], 0, 0, 0);
            acc[nt] = __builtin_amdgcn_mfma_f32_16x16x32_f16(a_hi, bhi, acc[nt], 0, 0, 0);
        }
        #pragma unroll
        for (int nt = 0; nt < 4; ++nt) {
            const int col = c * 256 + wave * 64 + nt * 16 + row;
            const float b = bias[col];
            #pragma unroll
            for (int r = 0; r < 4; ++r)
                out[(size_t)(m0 + kg * 4 + r) * OUT_F + col] = (acc[nt][r] + b) * scaling;
        }
    }
}

// ---------------------------------------------------------------------------
extern "C" void kernel_launch(void* const* d_in, const int* in_sizes, int n_in,
                              void* d_out, int out_size, void* d_ws, size_t ws_size,
                              hipStream_t stream) {
    (void)in_sizes; (void)n_in; (void)out_size;
    const float* x     = (const float*)d_in[0];
    const float* w_in  = (const float*)d_in[1];
    const float* w_out = (const float*)d_in[2];
    const float* bias  = (const float*)d_in[3];
    const float* s_in  = (const float*)d_in[4];
    const float* s_out = (const float*)d_in[5];

    const size_t need = (size_t)(RANK * IN_F + OUT_F * RANK) * sizeof(_Float16); // 1 MiB
    if (d_ws != nullptr && ws_size >= need) {
        _Float16* sw_in  = (_Float16*)d_ws;
        _Float16* sw_out = sw_in + (size_t)RANK * IN_F;
        prep_kernel<<<(RANK * IN_F + OUT_F * RANK) / 8 / 256, 256, 0, stream>>>(
            w_in, w_out, s_in, s_out, sw_in, sw_out);
        loro_main<<<M_TOT / 16, 256, 0, stream>>>(x, sw_in, sw_out, bias, (float*)d_out);
    } else {
        loro_fallback<<<M_TOT / 16, 256, 0, stream>>>(
            x, w_in, w_out, bias, s_in, s_out, (float*)d_out);
    }
}